// Round 5
// baseline (12631.753 us; speedup 1.0000x reference)
//
#include <hip/hip_runtime.h>
#include <math.h>

#define NN 100000
#define EE 1600000

// Strategy (round 3/4/5): edge-per-thread, acc[64] in VGPRs (launch_bounds(256,2)
// caps occupancy at 2 waves/EU -> 256 VGPR budget -> no spill), weights staged
// ONCE per block into LDS and read as wave-uniform broadcast ds_read_b128.
// Rounds 1-2 were L2-latency/traffic bound re-reading weights per edge
// (VALUBusy 8-9%); WRITE_SIZE 3.3GB is the m_i atomics (102M x 32B), kept.

__device__ __forceinline__ float silu_f(float x) {
    const float e = __expf(-x);
    return x * __builtin_amdgcn_rcpf(1.0f + e);
}

// acc[0..63] += x * w[0..63]; w points into LDS (broadcast) or global (uniform)
__device__ __forceinline__ void fmarow(float* acc, const float x, const float* __restrict__ w) {
#pragma unroll
    for (int c = 0; c < 16; ++c) {
        const float4 wv = *reinterpret_cast<const float4*>(w + 4 * c);
        acc[4 * c + 0] = fmaf(x, wv.x, acc[4 * c + 0]);
        acc[4 * c + 1] = fmaf(x, wv.y, acc[4 * c + 1]);
        acc[4 * c + 2] = fmaf(x, wv.z, acc[4 * c + 2]);
        acc[4 * c + 3] = fmaf(x, wv.w, acc[4 * c + 3]);
    }
}

// acc += x_vec[0..4*NV) @ W rows (W row-major [*,64])
template <int NV>
__device__ __forceinline__ void seg(float* acc, const float4* __restrict__ xsrc,
                                    const float* __restrict__ w) {
#pragma unroll 1
    for (int c = 0; c < NV; ++c) {
        const float4 xv = xsrc[c];
        const float* wr = w + (size_t)(4 * c) * 64;
        fmarow(acc, xv.x, wr);
        fmarow(acc, xv.y, wr + 64);
        fmarow(acc, xv.z, wr + 128);
        fmarow(acc, xv.w, wr + 192);
    }
}

__global__ void __launch_bounds__(256)
init_kernel(const float* __restrict__ pos, float* __restrict__ m_i,
            float* __restrict__ pos_out)
{
    const int i = blockIdx.x * 256 + threadIdx.x;
    const float4 z = make_float4(0.f, 0.f, 0.f, 0.f);
    if (i < NN * 64 / 4) reinterpret_cast<float4*>(m_i)[i] = z;
    if (i < NN * 3 / 4)
        reinterpret_cast<float4*>(pos_out)[i] = reinterpret_cast<const float4*>(pos)[i];
}

// LDS: W1[177*64]=11328f, W2[64*64]=4096f, B[256]: eb1|eb2|cb1|cw2
// total 15680 floats = 62720 B  (<64KB, 2 blocks/CU)
__global__ void __launch_bounds__(256, 2)
edge_kernel(const float* __restrict__ h, const float* __restrict__ pos,
            const float* __restrict__ ea, const float* __restrict__ te,
            const int* __restrict__ ei,
            const float* __restrict__ ew1, const float* __restrict__ eb1,
            const float* __restrict__ ew2, const float* __restrict__ eb2,
            const float* __restrict__ cw1, const float* __restrict__ cb1,
            const float* __restrict__ cw2,
            float* __restrict__ m_i, float* __restrict__ pos_out)
{
    extern __shared__ float lds[];
    float* W1 = lds;             // 11328
    float* W2 = lds + 11328;     // 4096
    float* B  = lds + 15424;     // 256

    const int t = threadIdx.x;
    {   // stage weights once per block
        const float4* s1 = reinterpret_cast<const float4*>(ew1);
        float4* d1 = reinterpret_cast<float4*>(W1);
        for (int i = t; i < 11328 / 4; i += 256) d1[i] = s1[i];
        const float4* s2 = reinterpret_cast<const float4*>(ew2);
        float4* d2 = reinterpret_cast<float4*>(W2);
        for (int i = t; i < 4096 / 4; i += 256) d2[i] = s2[i];
        if (t < 64) { B[t] = eb1[t]; B[64 + t] = eb2[t]; B[128 + t] = cb1[t]; B[192 + t] = cw2[t]; }
    }
    __syncthreads();

    const int stride = gridDim.x * 256;
    for (int e = blockIdx.x * 256 + t; e < EE; e += stride) {
        const int row = ei[e];
        const int col = ei[EE + e];

        const float rx = pos[3 * row + 0] - pos[3 * col + 0];
        const float ry = pos[3 * row + 1] - pos[3 * col + 1];
        const float rz = pos[3 * row + 2] - pos[3 * col + 2];
        const float dist = sqrtf(rx * rx + ry * ry + rz * rz);

        // ---- layer 1: edge_input[177] @ W1 + eb1 ----
        float acc[64];
#pragma unroll
        for (int j = 0; j < 64; ++j) acc[j] = B[j];
        seg<16>(acc, reinterpret_cast<const float4*>(h + (size_t)row * 64), W1);
        seg<16>(acc, reinterpret_cast<const float4*>(h + (size_t)col * 64), W1 + 64 * 64);
        seg<4>(acc, reinterpret_cast<const float4*>(ea + (size_t)e * 16), W1 + 128 * 64);
        fmarow(acc, dist, W1 + 144 * 64);
        seg<8>(acc, reinterpret_cast<const float4*>(te + (size_t)row * 32), W1 + 145 * 64);

        float tt[64];
#pragma unroll
        for (int j = 0; j < 64; ++j) tt[j] = silu_f(acc[j]);

        // ---- layer 2: silu(tt @ W2 + eb2) = m_ij ----
        float m[64];
#pragma unroll
        for (int j = 0; j < 64; ++j) m[j] = B[64 + j];
#pragma unroll
        for (int k = 0; k < 64; ++k) fmarow(m, tt[k], W2 + k * 64);
#pragma unroll
        for (int j = 0; j < 64; ++j) m[j] = silu_f(m[j]);

        // ---- scatter m_ij -> m_i[col] (fire-and-forget) ----
        float* md = m_i + (size_t)col * 64;
#pragma unroll
        for (int j = 0; j < 64; ++j) unsafeAtomicAdd(md + j, m[j]);

        // ---- coord MLP: silu(m @ cw1 + cb1) . cw2 ----
        // cw1 streamed from global (wave-uniform, L2-resident broadcast)
        float a3[64];
#pragma unroll
        for (int j = 0; j < 64; ++j) a3[j] = B[128 + j];
#pragma unroll
        for (int k = 0; k < 64; ++k) fmarow(a3, m[k], cw1 + (size_t)k * 64);

        float cwt = 0.0f;
#pragma unroll
        for (int j = 0; j < 64; ++j) cwt += silu_f(a3[j]) * B[192 + j];

        const float s = cwt / (dist + 1e-8f);
        unsafeAtomicAdd(&pos_out[3 * (size_t)col + 0], s * rx);
        unsafeAtomicAdd(&pos_out[3 * (size_t)col + 1], s * ry);
        unsafeAtomicAdd(&pos_out[3 * (size_t)col + 2], s * rz);
    }
}

// LDS: NW1[160*64]=10240f, NW2[64*64]=4096f, B[256]: nb1|nb2|sb|tb
// total 14592 floats = 58368 B
__global__ void __launch_bounds__(256, 2)
node_kernel(const float* __restrict__ h, const float* __restrict__ te,
            const float* __restrict__ m_i,
            const float* __restrict__ nw1, const float* __restrict__ nb1,
            const float* __restrict__ nw2, const float* __restrict__ nb2,
            const float* __restrict__ sw, const float* __restrict__ sb,
            const float* __restrict__ tw, const float* __restrict__ tb,
            float* __restrict__ h_out)
{
    extern __shared__ float lds[];
    float* W1 = lds;             // 10240
    float* W2 = lds + 10240;     // 4096
    float* B  = lds + 14336;     // 256

    const int t = threadIdx.x;
    {
        const float4* s1 = reinterpret_cast<const float4*>(nw1);
        float4* d1 = reinterpret_cast<float4*>(W1);
        for (int i = t; i < 10240 / 4; i += 256) d1[i] = s1[i];
        const float4* s2 = reinterpret_cast<const float4*>(nw2);
        float4* d2 = reinterpret_cast<float4*>(W2);
        for (int i = t; i < 4096 / 4; i += 256) d2[i] = s2[i];
        if (t < 64) { B[t] = nb1[t]; B[64 + t] = nb2[t]; B[128 + t] = sb[t]; B[192 + t] = tb[t]; }
    }
    __syncthreads();

    const int stride = gridDim.x * 256;
    for (int n = blockIdx.x * 256 + t; n < NN; n += stride) {
        const float4* hv = reinterpret_cast<const float4*>(h + (size_t)n * 64);
        const float4* tev = reinterpret_cast<const float4*>(te + (size_t)n * 32);

        // ---- layer 1: [h, m_i, te] @ NW1 + nb1 ----
        float acc[64];
#pragma unroll
        for (int j = 0; j < 64; ++j) acc[j] = B[j];
        seg<16>(acc, hv, W1);
        seg<16>(acc, reinterpret_cast<const float4*>(m_i + (size_t)n * 64), W1 + 64 * 64);
        seg<8>(acc, tev, W1 + 128 * 64);

        float tt[64];
#pragma unroll
        for (int j = 0; j < 64; ++j) tt[j] = silu_f(acc[j]);

        // ---- layer 2: tt @ NW2 + nb2 -> hu ----
        float hu[64];
#pragma unroll
        for (int j = 0; j < 64; ++j) hu[j] = B[64 + j];
#pragma unroll
        for (int k = 0; k < 64; ++k) fmarow(hu, tt[k], W2 + k * 64);

        // ---- FiLM scale (te @ sw + sb), global-uniform weight reads ----
        float f[64];
#pragma unroll
        for (int j = 0; j < 64; ++j) f[j] = B[128 + j];
        seg<8>(f, tev, sw);
#pragma unroll
        for (int j = 0; j < 64; ++j) hu[j] *= f[j];

        // ---- FiLM shift (te @ tw + tb) ----
#pragma unroll
        for (int j = 0; j < 64; ++j) f[j] = B[192 + j];
        seg<8>(f, tev, tw);

        // ---- h_new = h + hu + f ----
        float* op = h_out + (size_t)n * 64;
#pragma unroll
        for (int c = 0; c < 16; ++c) {
            const float4 hx = hv[c];
            float4 o;
            o.x = hx.x + hu[4 * c + 0] + f[4 * c + 0];
            o.y = hx.y + hu[4 * c + 1] + f[4 * c + 1];
            o.z = hx.z + hu[4 * c + 2] + f[4 * c + 2];
            o.w = hx.w + hu[4 * c + 3] + f[4 * c + 3];
            *reinterpret_cast<float4*>(op + 4 * c) = o;
        }
    }
}

extern "C" void kernel_launch(void* const* d_in, const int* in_sizes, int n_in,
                              void* d_out, int out_size, void* d_ws, size_t ws_size,
                              hipStream_t stream)
{
    const float* h    = (const float*)d_in[0];
    const float* pos  = (const float*)d_in[1];
    const float* ea   = (const float*)d_in[2];
    const float* te   = (const float*)d_in[3];
    const int*   ei   = (const int*)d_in[4];
    const float* ew1  = (const float*)d_in[5];
    const float* eb1  = (const float*)d_in[6];
    const float* ew2  = (const float*)d_in[7];
    const float* eb2  = (const float*)d_in[8];
    const float* nw1  = (const float*)d_in[9];
    const float* nb1  = (const float*)d_in[10];
    const float* nw2  = (const float*)d_in[11];
    const float* nb2  = (const float*)d_in[12];
    const float* cw1  = (const float*)d_in[13];
    const float* cb1  = (const float*)d_in[14];
    const float* cw2  = (const float*)d_in[15];
    const float* sw   = (const float*)d_in[16];
    const float* sb   = (const float*)d_in[17];
    const float* tw   = (const float*)d_in[18];
    const float* tb   = (const float*)d_in[19];

    float* h_out   = (float*)d_out;
    float* pos_out = (float*)d_out + (size_t)NN * 64;
    float* m_i     = (float*)d_ws;   // [N,64] accumulator

    init_kernel<<<(NN * 64 / 4 + 255) / 256, 256, 0, stream>>>(pos, m_i, pos_out);

    // persistent grid: 2 blocks/CU x 256 CU
    edge_kernel<<<512, 256, 62720, stream>>>(h, pos, ea, te, ei,
                                             ew1, eb1, ew2, eb2,
                                             cw1, cb1, cw2,
                                             m_i, pos_out);

    node_kernel<<<(NN + 255) / 256, 256, 58368, stream>>>(h, te, m_i,
                                                          nw1, nb1, nw2, nb2,
                                                          sw, sb, tw, tb, h_out);
}